// Round 18
// baseline (318.629 us; speedup 1.0000x reference)
//
#include <hip/hip_runtime.h>

// GCN_17377437680138: 3-layer GCN + relu + per-layer global_add_pool, concat.
// N=100000, E=1600000, F=H=64, 64 graphs, fp32 in/out.
// R13: R12 + nontemporal edge-list reads in k_build (streaming reads were
// evicting the 2.4 MB/XCD dirty CSR working set from L2 before neighbor
// writes could merge -> 78 MB write-amp). CSR writes stay cached.

#define F 64
#define CAP 48
#define NRANGE 8

typedef __attribute__((ext_vector_type(8))) short short8x;
typedef __attribute__((ext_vector_type(8))) unsigned short ushort8x;
typedef __attribute__((ext_vector_type(4))) float f32x4;
typedef __attribute__((ext_vector_type(4))) int int4x;

static inline size_t alignup(size_t x, size_t a) { return (x + a - 1) & ~(a - 1); }

__device__ __forceinline__ ushort f2bf(float f) {
    unsigned u = __builtin_bit_cast(unsigned, f);
    unsigned r = (u + 0x7fffu + ((u >> 16) & 1u)) >> 16;  // RNE
    return (ushort)r;
}
__device__ __forceinline__ float bf2f(ushort v) {
    return __builtin_bit_cast(float, ((unsigned)v) << 16);
}

// Dest-range-partitioned padded-CSR build; edge reads nontemporal (keep L2 for
// the dirty CSR lines so neighboring writes merge before eviction).
__global__ __launch_bounds__(256) void k_build(const int* __restrict__ rowv,
                                               const int* __restrict__ colv,
                                               int* __restrict__ cnt,
                                               int* __restrict__ csr,
                                               int E, int rsize) {
    int r = blockIdx.x & (NRANGE - 1);
    int e4 = (blockIdx.x >> 3) * 256 + threadIdx.x;
    int lo = r * rsize;
    int hiEx = lo + rsize;
    int E4 = E >> 2;
    if (e4 < E4) {
        int4x c = __builtin_nontemporal_load((const int4x*)colv + e4);
        int4x s = __builtin_nontemporal_load((const int4x*)rowv + e4);
        int p;
        if (c[0] >= lo && c[0] < hiEx) {
            p = atomicAdd(&cnt[c[0]], 1);
            if (p < CAP) csr[(size_t)c[0] * CAP + p] = s[0];
        }
        if (c[1] >= lo && c[1] < hiEx) {
            p = atomicAdd(&cnt[c[1]], 1);
            if (p < CAP) csr[(size_t)c[1] * CAP + p] = s[1];
        }
        if (c[2] >= lo && c[2] < hiEx) {
            p = atomicAdd(&cnt[c[2]], 1);
            if (p < CAP) csr[(size_t)c[2] * CAP + p] = s[2];
        }
        if (c[3] >= lo && c[3] < hiEx) {
            p = atomicAdd(&cnt[c[3]], 1);
            if (p < CAP) csr[(size_t)c[3] * CAP + p] = s[3];
        }
    }
    int tail = E & 3;
    if (r == 0 && (int)blockIdx.x < NRANGE && (int)threadIdx.x < tail) {
        int e = (E4 << 2) + threadIdx.x;
        int c = colv[e], s = rowv[e];
        int p = atomicAdd(&cnt[c], 1);
        if (p < CAP) csr[(size_t)c * CAP + p] = s;
    }
}

// x (f32) -> bf16 flat
__global__ __launch_bounds__(256) void k_prepx(const float* __restrict__ x,
                                               ushort* __restrict__ xbf, long n4) {
    long i = (long)blockIdx.x * 256 + threadIdx.x;
    if (i < n4) {
        float4 v = ((const float4*)x)[i];
        ushort4 u;
        u.x = f2bf(v.x); u.y = f2bf(v.y); u.z = f2bf(v.z); u.w = f2bf(v.w);
        ((ushort4*)xbf)[i] = u;
    }
}

// W_l [64][64] f32 -> WT_l [c][k] bf16
__global__ __launch_bounds__(256) void k_prepw(const float* __restrict__ W0,
                                               const float* __restrict__ W1,
                                               const float* __restrict__ W2,
                                               ushort* __restrict__ wt) {
    const float* W = (blockIdx.x == 0) ? W0 : (blockIdx.x == 1) ? W1 : W2;
    ushort* o = wt + (size_t)blockIdx.x * F * F;
    for (int i = threadIdx.x; i < F * F; i += 256) {
        int k = i >> 6, c = i & 63;
        o[c * F + k] = f2bf(W[i]);
    }
}

// MFMA GEMM (R7): XW[r][c] = (sum_k Hbf[r][k] * W[k][c]) * rsqrt(deg[r]+1), bf16.
__global__ __launch_bounds__(256) void k_gemm(const ushort* __restrict__ Hbf,
                                              const ushort* __restrict__ WT,
                                              const int* __restrict__ cnt,
                                              ushort* __restrict__ XW, int n) {
    __shared__ ushort hl[64][72];
    __shared__ ushort wl[64][72];
    int rowBase = blockIdx.x * 64;
    for (int i = threadIdx.x; i < 1024; i += 256) {
        int idx = i & 511;
        int row = idx >> 3, cb = (idx & 7) << 3;
        if (i < 512) {
            int gr = rowBase + row;
            short8x v = {0, 0, 0, 0, 0, 0, 0, 0};
            if (gr < n) v = *(const short8x*)(Hbf + (size_t)gr * F + cb);
            *(short8x*)&hl[row][cb] = v;
        } else {
            *(short8x*)&wl[row][cb] = *(const short8x*)(WT + row * F + cb);
        }
    }
    __syncthreads();

    int lane = threadIdx.x & 63;
    int w = threadIdx.x >> 6;
    int l15 = lane & 15, l4 = lane >> 4;

    short8x a0 = *(const short8x*)&hl[w * 16 + l15][l4 * 8];
    short8x a1 = *(const short8x*)&hl[w * 16 + l15][32 + l4 * 8];

    f32x4 acc[4];
#pragma unroll
    for (int ct = 0; ct < 4; ++ct) {
        acc[ct] = (f32x4){0.f, 0.f, 0.f, 0.f};
        short8x b0 = *(const short8x*)&wl[ct * 16 + l15][l4 * 8];
        short8x b1 = *(const short8x*)&wl[ct * 16 + l15][32 + l4 * 8];
        acc[ct] = __builtin_amdgcn_mfma_f32_16x16x32_bf16(a0, b0, acc[ct], 0, 0, 0);
        acc[ct] = __builtin_amdgcn_mfma_f32_16x16x32_bf16(a1, b1, acc[ct], 0, 0, 0);
    }

#pragma unroll
    for (int r = 0; r < 4; ++r) {
        int gr = rowBase + w * 16 + l4 * 4 + r;
        if (gr < n) {
            float sc = rsqrtf((float)cnt[gr] + 1.0f);
#pragma unroll
            for (int ct = 0; ct < 4; ++ct) {
                XW[(size_t)gr * F + ct * 16 + l15] = f2bf(acc[ct][r] * sc);
            }
        }
    }
}

// Gather + fused pool (R12). Block = 4 waves x 8 nodes = 32 consecutive nodes.
__global__ __launch_bounds__(256) void k_gather(const ushort* __restrict__ XW,
                                                const int* __restrict__ cnt,
                                                const int* __restrict__ csr,
                                                const float* __restrict__ bias,
                                                const int* __restrict__ batch,
                                                ushort* __restrict__ h,
                                                float* __restrict__ out,
                                                int layerOff, int n, int writeH) {
    __shared__ float bins[32][F];
    __shared__ int binfo[2];  // b0, bspan
    for (int i = threadIdx.x; i < 32 * F; i += 256) ((float*)bins)[i] = 0.f;
    int blockStart = blockIdx.x * 32;
    if (threadIdx.x == 0) {
        int b0 = batch[min(blockStart, n - 1)];
        int bl = batch[min(blockStart + 31, n - 1)];
        binfo[0] = b0;
        binfo[1] = bl - b0;
    }
    __syncthreads();

    int lane = threadIdx.x & 63;
    int q = lane >> 3, s = lane & 7;
    int wave = threadIdx.x >> 6;
    int node = blockStart + wave * 8 + q;

    if (node < n) {
        float4 bv0 = ((const float4*)bias)[s * 2];
        float4 bv1 = ((const float4*)bias)[s * 2 + 1];

        int deg = cnt[node];
        int dmax = min(deg, CAP);
        const int* cr = csr + (size_t)node * CAP;
        const ushort8x* rows = (const ushort8x*)XW;

        float sum[8];
        {
            ushort8x v = rows[(size_t)node * 8 + s];  // self loop (dinv folded in XW)
#pragma unroll
            for (int i = 0; i < 8; ++i) sum[i] = bf2f(v[i]);
        }
        int j = 0;
        for (; j + 4 <= dmax; j += 4) {
            int4 a = *(const int4*)(cr + j);
            ushort8x v0 = rows[(size_t)a.x * 8 + s];
            ushort8x v1 = rows[(size_t)a.y * 8 + s];
            ushort8x v2 = rows[(size_t)a.z * 8 + s];
            ushort8x v3 = rows[(size_t)a.w * 8 + s];
#pragma unroll
            for (int i = 0; i < 8; ++i)
                sum[i] += (bf2f(v0[i]) + bf2f(v1[i])) + (bf2f(v2[i]) + bf2f(v3[i]));
        }
        for (; j < dmax; ++j) {
            ushort8x v = rows[(size_t)cr[j] * 8 + s];
#pragma unroll
            for (int i = 0; i < 8; ++i) sum[i] += bf2f(v[i]);
        }

        float sc = rsqrtf((float)deg + 1.0f);
        float val[8];
        val[0] = fmaxf(fmaf(sum[0], sc, bv0.x), 0.f);
        val[1] = fmaxf(fmaf(sum[1], sc, bv0.y), 0.f);
        val[2] = fmaxf(fmaf(sum[2], sc, bv0.z), 0.f);
        val[3] = fmaxf(fmaf(sum[3], sc, bv0.w), 0.f);
        val[4] = fmaxf(fmaf(sum[4], sc, bv1.x), 0.f);
        val[5] = fmaxf(fmaf(sum[5], sc, bv1.y), 0.f);
        val[6] = fmaxf(fmaf(sum[6], sc, bv1.z), 0.f);
        val[7] = fmaxf(fmaf(sum[7], sc, bv1.w), 0.f);

        if (writeH) {
            ushort8x o;
#pragma unroll
            for (int i = 0; i < 8; ++i) o[i] = f2bf(val[i]);
            ((ushort8x*)h)[(size_t)node * 8 + s] = o;
        }

        int k = batch[node] - binfo[0];
        float* bin = &bins[k][s * 8];
#pragma unroll
        for (int i = 0; i < 8; ++i) atomicAdd(&bin[i], val[i]);
    }
    __syncthreads();

    int b0 = binfo[0], bspan = binfo[1];
    for (int k = 0; k <= bspan; ++k) {
        if (threadIdx.x < F) {
            atomicAdd(&out[(b0 + k) * (3 * F) + layerOff + threadIdx.x],
                      bins[k][threadIdx.x]);
        }
    }
}

extern "C" void kernel_launch(void* const* d_in, const int* in_sizes, int n_in,
                              void* d_out, int out_size, void* d_ws, size_t ws_size,
                              hipStream_t stream) {
    const float* x = (const float*)d_in[0];
    const int* edge = (const int*)d_in[1];   // [2,E]: first E = row(src), next E = col(dst)
    const int* batch = (const int*)d_in[2];
    const float* Ws[3] = {(const float*)d_in[3], (const float*)d_in[5], (const float*)d_in[7]};
    const float* bs[3] = {(const float*)d_in[4], (const float*)d_in[6], (const float*)d_in[8]};
    float* out = (float*)d_out;

    const int N = in_sizes[0] / F;
    const int E = in_sizes[1] / 2;
    const int* rowv = edge;
    const int* colv = edge + E;

    // workspace layout (~58 MB)
    char* ws = (char*)d_ws;
    size_t off = 0;
    int*    cnt = (int*)(ws + off);    off = alignup(off + (size_t)N * 4, 256);
    int*    csr = (int*)(ws + off);    off = alignup(off + (size_t)N * CAP * 4, 256);
    ushort* xw  = (ushort*)(ws + off); off = alignup(off + (size_t)N * F * 2, 256);
    ushort* h   = (ushort*)(ws + off); off = alignup(off + (size_t)N * F * 2, 256);
    ushort* xbf = (ushort*)(ws + off); off = alignup(off + (size_t)N * F * 2, 256);
    ushort* wt  = (ushort*)(ws + off); off = alignup(off + (size_t)3 * F * F * 2, 256);
    (void)ws_size;

    hipMemsetAsync(out, 0, (size_t)out_size * sizeof(float), stream);
    hipMemsetAsync(cnt, 0, (size_t)N * 4, stream);

    const int rsize = (N + NRANGE - 1) / NRANGE;
    const int chunks = ((E >> 2) + 255) / 256;
    k_build<<<chunks * NRANGE, 256, 0, stream>>>(rowv, colv, cnt, csr, E, rsize);

    const long n4 = ((long)N * F) / 4;
    k_prepx<<<(int)((n4 + 255) / 256), 256, 0, stream>>>(x, xbf, n4);
    k_prepw<<<3, 256, 0, stream>>>(Ws[0], Ws[1], Ws[2], wt);

    const int gemmBlocks = (N + 63) / 64;
    const int gatherBlocks = (N + 31) / 32;

    for (int l = 0; l < 3; ++l) {
        const ushort* Hin = (l == 0) ? xbf : h;
        k_gemm<<<gemmBlocks, 256, 0, stream>>>(Hin, wt + (size_t)l * F * F, cnt, xw, N);
        k_gather<<<gatherBlocks, 256, 0, stream>>>(xw, cnt, csr, bs[l], batch, h, out,
                                                   l * F, N, (l < 2) ? 1 : 0);
    }
}

// Round 19
// 309.122 us; speedup vs baseline: 1.0308x; 1.0308x over previous
//
#include <hip/hip_runtime.h>

// GCN_17377437680138: 3-layer GCN + relu + per-layer global_add_pool, concat.
// N=100000, E=1600000, F=H=64, 64 graphs, fp32 in/out.
// R14: R12 baseline (NT loads reverted — they traded L2 edge-stream hits for
// write-amp, net wash) + single fused k_prep dispatch (zero out, zero cnt,
// x->bf16, W->WT bf16): 13 -> 8 dispatches, ~5 launch gaps saved.

#define F 64
#define CAP 48
#define NRANGE 8

typedef __attribute__((ext_vector_type(8))) short short8x;
typedef __attribute__((ext_vector_type(8))) unsigned short ushort8x;
typedef __attribute__((ext_vector_type(4))) float f32x4;

static inline size_t alignup(size_t x, size_t a) { return (x + a - 1) & ~(a - 1); }

__device__ __forceinline__ ushort f2bf(float f) {
    unsigned u = __builtin_bit_cast(unsigned, f);
    unsigned r = (u + 0x7fffu + ((u >> 16) & 1u)) >> 16;  // RNE
    return (ushort)r;
}
__device__ __forceinline__ float bf2f(ushort v) {
    return __builtin_bit_cast(float, ((unsigned)v) << 16);
}

// Dest-range-partitioned padded-CSR build (R6/R12, plain cached loads).
__global__ __launch_bounds__(256) void k_build(const int* __restrict__ rowv,
                                               const int* __restrict__ colv,
                                               int* __restrict__ cnt,
                                               int* __restrict__ csr,
                                               int E, int rsize) {
    int r = blockIdx.x & (NRANGE - 1);
    int e4 = (blockIdx.x >> 3) * 256 + threadIdx.x;
    int lo = r * rsize;
    int hiEx = lo + rsize;
    int E4 = E >> 2;
    if (e4 < E4) {
        int4 c = ((const int4*)colv)[e4];
        int4 s = ((const int4*)rowv)[e4];
        int p;
        if (c.x >= lo && c.x < hiEx) {
            p = atomicAdd(&cnt[c.x], 1);
            if (p < CAP) csr[(size_t)c.x * CAP + p] = s.x;
        }
        if (c.y >= lo && c.y < hiEx) {
            p = atomicAdd(&cnt[c.y], 1);
            if (p < CAP) csr[(size_t)c.y * CAP + p] = s.y;
        }
        if (c.z >= lo && c.z < hiEx) {
            p = atomicAdd(&cnt[c.z], 1);
            if (p < CAP) csr[(size_t)c.z * CAP + p] = s.z;
        }
        if (c.w >= lo && c.w < hiEx) {
            p = atomicAdd(&cnt[c.w], 1);
            if (p < CAP) csr[(size_t)c.w * CAP + p] = s.w;
        }
    }
    int tail = E & 3;
    if (r == 0 && (int)blockIdx.x < NRANGE && (int)threadIdx.x < tail) {
        int e = (E4 << 2) + threadIdx.x;
        int c = colv[e], s = rowv[e];
        int p = atomicAdd(&cnt[c], 1);
        if (p < CAP) csr[(size_t)c * CAP + p] = s;
    }
}

// Fused prep: [0,PX) x->bf16; [PX,PX+3) W_l->WT_l; PX+3 zero out; [PX+4..) zero cnt.
__global__ __launch_bounds__(256) void k_prep(const float* __restrict__ x,
                                              ushort* __restrict__ xbf,
                                              const float* __restrict__ W0,
                                              const float* __restrict__ W1,
                                              const float* __restrict__ W2,
                                              ushort* __restrict__ wt,
                                              float* __restrict__ out, int outsz,
                                              int* __restrict__ cnt,
                                              long n4, int n, int PX) {
    int b = blockIdx.x;
    if (b < PX) {
        long i = (long)b * 256 + threadIdx.x;
        if (i < n4) {
            float4 v = ((const float4*)x)[i];
            ushort4 u;
            u.x = f2bf(v.x); u.y = f2bf(v.y); u.z = f2bf(v.z); u.w = f2bf(v.w);
            ((ushort4*)xbf)[i] = u;
        }
        return;
    }
    b -= PX;
    if (b < 3) {
        const float* W = (b == 0) ? W0 : (b == 1) ? W1 : W2;
        ushort* o = wt + (size_t)b * F * F;
        for (int i = threadIdx.x; i < F * F; i += 256) {
            int k = i >> 6, c = i & 63;
            o[c * F + k] = f2bf(W[i]);
        }
        return;
    }
    if (b == 3) {
        for (int i = threadIdx.x; i < outsz; i += 256) out[i] = 0.f;
        return;
    }
    // zero cnt: blocks [4 ..), each covers 256*16 ints
    int base = (b - 4) * 256 * 16 + threadIdx.x * 16;
#pragma unroll
    for (int c = 0; c < 4; ++c) {
        int idx = base + c * 4;
        if (idx + 3 < n) *(int4*)(cnt + idx) = make_int4(0, 0, 0, 0);
        else for (int t = 0; t < 4; ++t) if (idx + t < n) cnt[idx + t] = 0;
    }
}

// MFMA GEMM (R7): XW[r][c] = (sum_k Hbf[r][k] * W[k][c]) * rsqrt(deg[r]+1), bf16.
__global__ __launch_bounds__(256) void k_gemm(const ushort* __restrict__ Hbf,
                                              const ushort* __restrict__ WT,
                                              const int* __restrict__ cnt,
                                              ushort* __restrict__ XW, int n) {
    __shared__ ushort hl[64][72];
    __shared__ ushort wl[64][72];
    int rowBase = blockIdx.x * 64;
    for (int i = threadIdx.x; i < 1024; i += 256) {
        int idx = i & 511;
        int row = idx >> 3, cb = (idx & 7) << 3;
        if (i < 512) {
            int gr = rowBase + row;
            short8x v = {0, 0, 0, 0, 0, 0, 0, 0};
            if (gr < n) v = *(const short8x*)(Hbf + (size_t)gr * F + cb);
            *(short8x*)&hl[row][cb] = v;
        } else {
            *(short8x*)&wl[row][cb] = *(const short8x*)(WT + row * F + cb);
        }
    }
    __syncthreads();

    int lane = threadIdx.x & 63;
    int w = threadIdx.x >> 6;
    int l15 = lane & 15, l4 = lane >> 4;

    short8x a0 = *(const short8x*)&hl[w * 16 + l15][l4 * 8];
    short8x a1 = *(const short8x*)&hl[w * 16 + l15][32 + l4 * 8];

    f32x4 acc[4];
#pragma unroll
    for (int ct = 0; ct < 4; ++ct) {
        acc[ct] = (f32x4){0.f, 0.f, 0.f, 0.f};
        short8x b0 = *(const short8x*)&wl[ct * 16 + l15][l4 * 8];
        short8x b1 = *(const short8x*)&wl[ct * 16 + l15][32 + l4 * 8];
        acc[ct] = __builtin_amdgcn_mfma_f32_16x16x32_bf16(a0, b0, acc[ct], 0, 0, 0);
        acc[ct] = __builtin_amdgcn_mfma_f32_16x16x32_bf16(a1, b1, acc[ct], 0, 0, 0);
    }

#pragma unroll
    for (int r = 0; r < 4; ++r) {
        int gr = rowBase + w * 16 + l4 * 4 + r;
        if (gr < n) {
            float sc = rsqrtf((float)cnt[gr] + 1.0f);
#pragma unroll
            for (int ct = 0; ct < 4; ++ct) {
                XW[(size_t)gr * F + ct * 16 + l15] = f2bf(acc[ct][r] * sc);
            }
        }
    }
}

// Gather + fused pool (R12). Block = 4 waves x 8 nodes = 32 consecutive nodes.
__global__ __launch_bounds__(256) void k_gather(const ushort* __restrict__ XW,
                                                const int* __restrict__ cnt,
                                                const int* __restrict__ csr,
                                                const float* __restrict__ bias,
                                                const int* __restrict__ batch,
                                                ushort* __restrict__ h,
                                                float* __restrict__ out,
                                                int layerOff, int n, int writeH) {
    __shared__ float bins[32][F];
    __shared__ int binfo[2];  // b0, bspan
    for (int i = threadIdx.x; i < 32 * F; i += 256) ((float*)bins)[i] = 0.f;
    int blockStart = blockIdx.x * 32;
    if (threadIdx.x == 0) {
        int b0 = batch[min(blockStart, n - 1)];
        int bl = batch[min(blockStart + 31, n - 1)];
        binfo[0] = b0;
        binfo[1] = bl - b0;
    }
    __syncthreads();

    int lane = threadIdx.x & 63;
    int q = lane >> 3, s = lane & 7;
    int wave = threadIdx.x >> 6;
    int node = blockStart + wave * 8 + q;

    if (node < n) {
        float4 bv0 = ((const float4*)bias)[s * 2];
        float4 bv1 = ((const float4*)bias)[s * 2 + 1];

        int deg = cnt[node];
        int dmax = min(deg, CAP);
        const int* cr = csr + (size_t)node * CAP;
        const ushort8x* rows = (const ushort8x*)XW;

        float sum[8];
        {
            ushort8x v = rows[(size_t)node * 8 + s];  // self loop (dinv folded in XW)
#pragma unroll
            for (int i = 0; i < 8; ++i) sum[i] = bf2f(v[i]);
        }
        int j = 0;
        for (; j + 4 <= dmax; j += 4) {
            int4 a = *(const int4*)(cr + j);
            ushort8x v0 = rows[(size_t)a.x * 8 + s];
            ushort8x v1 = rows[(size_t)a.y * 8 + s];
            ushort8x v2 = rows[(size_t)a.z * 8 + s];
            ushort8x v3 = rows[(size_t)a.w * 8 + s];
#pragma unroll
            for (int i = 0; i < 8; ++i)
                sum[i] += (bf2f(v0[i]) + bf2f(v1[i])) + (bf2f(v2[i]) + bf2f(v3[i]));
        }
        for (; j < dmax; ++j) {
            ushort8x v = rows[(size_t)cr[j] * 8 + s];
#pragma unroll
            for (int i = 0; i < 8; ++i) sum[i] += bf2f(v[i]);
        }

        float sc = rsqrtf((float)deg + 1.0f);
        float val[8];
        val[0] = fmaxf(fmaf(sum[0], sc, bv0.x), 0.f);
        val[1] = fmaxf(fmaf(sum[1], sc, bv0.y), 0.f);
        val[2] = fmaxf(fmaf(sum[2], sc, bv0.z), 0.f);
        val[3] = fmaxf(fmaf(sum[3], sc, bv0.w), 0.f);
        val[4] = fmaxf(fmaf(sum[4], sc, bv1.x), 0.f);
        val[5] = fmaxf(fmaf(sum[5], sc, bv1.y), 0.f);
        val[6] = fmaxf(fmaf(sum[6], sc, bv1.z), 0.f);
        val[7] = fmaxf(fmaf(sum[7], sc, bv1.w), 0.f);

        if (writeH) {
            ushort8x o;
#pragma unroll
            for (int i = 0; i < 8; ++i) o[i] = f2bf(val[i]);
            ((ushort8x*)h)[(size_t)node * 8 + s] = o;
        }

        int k = batch[node] - binfo[0];
        float* bin = &bins[k][s * 8];
#pragma unroll
        for (int i = 0; i < 8; ++i) atomicAdd(&bin[i], val[i]);
    }
    __syncthreads();

    int b0 = binfo[0], bspan = binfo[1];
    for (int k = 0; k <= bspan; ++k) {
        if (threadIdx.x < F) {
            atomicAdd(&out[(b0 + k) * (3 * F) + layerOff + threadIdx.x],
                      bins[k][threadIdx.x]);
        }
    }
}

extern "C" void kernel_launch(void* const* d_in, const int* in_sizes, int n_in,
                              void* d_out, int out_size, void* d_ws, size_t ws_size,
                              hipStream_t stream) {
    const float* x = (const float*)d_in[0];
    const int* edge = (const int*)d_in[1];   // [2,E]: first E = row(src), next E = col(dst)
    const int* batch = (const int*)d_in[2];
    const float* Ws[3] = {(const float*)d_in[3], (const float*)d_in[5], (const float*)d_in[7]};
    const float* bs[3] = {(const float*)d_in[4], (const float*)d_in[6], (const float*)d_in[8]};
    float* out = (float*)d_out;

    const int N = in_sizes[0] / F;
    const int E = in_sizes[1] / 2;
    const int* rowv = edge;
    const int* colv = edge + E;

    // workspace layout (~58 MB)
    char* ws = (char*)d_ws;
    size_t off = 0;
    int*    cnt = (int*)(ws + off);    off = alignup(off + (size_t)N * 4, 256);
    int*    csr = (int*)(ws + off);    off = alignup(off + (size_t)N * CAP * 4, 256);
    ushort* xw  = (ushort*)(ws + off); off = alignup(off + (size_t)N * F * 2, 256);
    ushort* h   = (ushort*)(ws + off); off = alignup(off + (size_t)N * F * 2, 256);
    ushort* xbf = (ushort*)(ws + off); off = alignup(off + (size_t)N * F * 2, 256);
    ushort* wt  = (ushort*)(ws + off); off = alignup(off + (size_t)3 * F * F * 2, 256);
    (void)ws_size;

    const long n4 = ((long)N * F) / 4;
    const int PX = (int)((n4 + 255) / 256);
    const int cntBlocks = (N + 256 * 16 - 1) / (256 * 16);

    k_prep<<<PX + 4 + cntBlocks, 256, 0, stream>>>(x, xbf, Ws[0], Ws[1], Ws[2], wt,
                                                   out, out_size, cnt, n4, N, PX);

    const int rsize = (N + NRANGE - 1) / NRANGE;
    const int chunks = ((E >> 2) + 255) / 256;
    k_build<<<chunks * NRANGE, 256, 0, stream>>>(rowv, colv, cnt, csr, E, rsize);

    const int gemmBlocks = (N + 63) / 64;
    const int gatherBlocks = (N + 31) / 32;

    for (int l = 0; l < 3; ++l) {
        const ushort* Hin = (l == 0) ? xbf : h;
        k_gemm<<<gemmBlocks, 256, 0, stream>>>(Hin, wt + (size_t)l * F * F, cnt, xw, N);
        k_gather<<<gatherBlocks, 256, 0, stream>>>(xw, cnt, csr, bs[l], batch, h, out,
                                                   l * F, N, (l < 2) ? 1 : 0);
    }
}